// Round 5
// baseline (284.124 us; speedup 1.0000x reference)
//
#include <hip/hip_runtime.h>
#include <hip/hip_cooperative_groups.h>

namespace cg = cooperative_groups;

// CASSI forward: Y[b,m,no] = sum_l H[m,no-l] * x[b,m,no-l,l], no in [0,542)
// then Y /= max(Y); output = [Y flat | H flat].  B=8, M=512, L=31, S=1.
//
// R5: ONE persistent cooperative kernel. 1536 blocks (6/CU guaranteed by
// __launch_bounds__(256,6); LDS 20.6KB -> 6/CU fits 124KB<160KB). Each block
// processes a CONTIGUOUS range of 10-11 (row,chunk) units: stage x slice via
// global_load_lds (width 16), gather from LDS (lane stride 31 f -> 2-way
// bank aliasing = free), keep Y in registers (statically indexed via full
// unroll). Block max -> ws[p]; grid.sync(); every block reduces the 1536
// maxes from L2 itself (no 2nd sync, no serial reduce block); write Y*inv
// once. Kills the 19MB normalize round-trip + 2 launches + memset.

#define MDIM    512
#define LBANDS  31
#define WOUT    (MDIM + LBANDS - 1)    // 542
#define BATCH   8
#define ROWELEMS (MDIM * LBANDS)       // 15872
#define CHUNK   136
#define NUNIT   (BATCH * MDIM * 4)     // 16384 (row,chunk) units
#define NBLK    1536
#define UPB     11                     // max units per block (1024*11+512*10)
#define MAXVEC  1288                   // float4 slots per slice

__global__ __launch_bounds__(256, 6) void cassi_fused_kernel(
    const float* __restrict__ x,      // (B, M, M, L)
    const float* __restrict__ Hm,     // (M, M)
    float* __restrict__ out,          // [Y (B*M*WOUT) | H (M*M)]
    float* __restrict__ ws)           // NBLK block maxes
{
    __shared__ float xs[MAXVEC * 4];  // 20,608 B
    __shared__ float smax[4];

    const int tid = threadIdx.x;
    const int p   = blockIdx.x;
    // 16384 = 1024*11 + 512*10: blocks <1024 take 11 units, rest take 10.
    const int cnt   = (p < 1024) ? 11 : 10;
    const int start = (p < 1024) ? p * 11 : 11264 + (p - 1024) * 10;

    float lmax = 0.0f;
    float yv[UPB];

    // ---- H append (2MB, overlaps with x streaming); 65536 float4 total ----
    {
        const int idx = p * 256 + tid;
        if (idx < (MDIM * MDIM / 4)) {
            const float4* __restrict__ h4 = (const float4*)Hm;
            float4* o4 = (float4*)(out + (size_t)BATCH * MDIM * WOUT);
            o4[idx] = h4[idx];
        }
    }

    // ---- phase 1: compute units, Y kept in registers ----
    #pragma unroll
    for (int i = 0; i < UPB; ++i) {
        yv[i] = 0.0f;
        if (i < cnt) {
            const int u  = start + i;
            const int bm = u >> 2;                 // b*M + m
            const int c0 = (u & 3) * CHUNK;
            const int m  = bm & (MDIM - 1);
            int n0 = c0 - (LBANDS - 1); if (n0 < 0) n0 = 0;
            int n1 = c0 + CHUNK - 1;    if (n1 > MDIM - 1) n1 = MDIM - 1;
            const int gb   = (n0 * LBANDS) & ~3;           // 16B-aligned base
            const int nvec = ((n1 + 1) * LBANDS - gb + 3) >> 2;

            __syncthreads();   // prev unit's LDS reads done before overwrite
            const float* __restrict__ xsl = x + (size_t)bm * ROWELEMS + gb;
            for (int v = tid; v < nvec; v += 256)
                __builtin_amdgcn_global_load_lds(
                    (const __attribute__((address_space(1))) void*)(xsl + 4 * v),
                    (__attribute__((address_space(3))) void*)(xs + 4 * v),
                    16, 0, 0);
            __syncthreads();   // vmcnt drained by barrier semantics

            const int ncols = (WOUT - c0) < CHUNK ? (WOUT - c0) : CHUNK;
            if (tid < ncols) {
                const int no = c0 + tid;
                const float* __restrict__ hrow = Hm + m * MDIM;
                int l0 = no - (MDIM - 1); if (l0 < 0) l0 = 0;
                const int l1 = (no < LBANDS - 1) ? no : (LBANDS - 1);
                int e = (no - l0) * LBANDS + l0 - gb;  // lane stride 31: free
                int h = no - l0;
                float acc = 0.0f;
                for (int l = l0; l <= l1; ++l) {
                    acc = fmaf(hrow[h], xs[e], acc);
                    e -= (LBANDS - 1);
                    --h;
                }
                yv[i] = acc;
                lmax = fmaxf(lmax, acc);
            }
        }
    }

    // ---- block max -> ws[p] ----
    #pragma unroll
    for (int off = 32; off > 0; off >>= 1)
        lmax = fmaxf(lmax, __shfl_down(lmax, off, 64));
    if ((tid & 63) == 0) smax[tid >> 6] = lmax;
    __syncthreads();
    if (tid == 0)
        ws[p] = fmaxf(fmaxf(smax[0], smax[1]), fmaxf(smax[2], smax[3]));

    cg::this_grid().sync();

    // ---- every block reduces all 1536 maxes (L2-resident, 6KB) ----
    float gm = 0.0f;
    for (int i = tid; i < NBLK; i += 256) gm = fmaxf(gm, ws[i]);
    #pragma unroll
    for (int off = 32; off > 0; off >>= 1)
        gm = fmaxf(gm, __shfl_down(gm, off, 64));
    if ((tid & 63) == 0) smax[tid >> 6] = gm;
    __syncthreads();
    const float inv =
        1.0f / fmaxf(fmaxf(smax[0], smax[1]), fmaxf(smax[2], smax[3]));

    // ---- phase 2: write normalized Y from registers ----
    #pragma unroll
    for (int i = 0; i < UPB; ++i) {
        if (i < cnt) {
            const int u  = start + i;
            const int bm = u >> 2;
            const int c0 = (u & 3) * CHUNK;
            const int ncols = (WOUT - c0) < CHUNK ? (WOUT - c0) : CHUNK;
            if (tid < ncols)
                out[(size_t)bm * WOUT + c0 + tid] = yv[i] * inv;
        }
    }
}

extern "C" void kernel_launch(void* const* d_in, const int* in_sizes, int n_in,
                              void* d_out, int out_size, void* d_ws, size_t ws_size,
                              hipStream_t stream) {
    const float* x  = (const float*)d_in[0];   // (8, 512, 512, 31, 1)
    const float* Hm = (const float*)d_in[1];   // (1, 512, 512, 1, 1)
    float* out = (float*)d_out;                // [Y | H]
    float* ws  = (float*)d_ws;                 // 1536 block maxes

    void* args[] = {(void*)&x, (void*)&Hm, (void*)&out, (void*)&ws};
    hipLaunchCooperativeKernel(reinterpret_cast<void*>(cassi_fused_kernel),
                               dim3(NBLK), dim3(256), args, 0, stream);
}

// Round 6
// 59.902 us; speedup vs baseline: 4.7431x; 4.7431x over previous
//
#include <hip/hip_runtime.h>

// CASSI forward: Y[b,m,no] = sum_l H[m,no-l] * x[b,m,no-l,l], no in [0,542)
// then Y /= max(Y); output = [Y flat | H flat].  B=8, M=512, L=31, S=1.
//
// R6 = R4 structure (one (row,chunk) unit per block, massive TLP) + fixes:
//  - CHUNK=128, block=128: every lane owns one output column (no idle lanes).
//  - Fully unrolled 31-tap gather, single code path: indices clamped, tap
//    masked via cndmask -> batched ds_reads, no serial dep chain, no branch
//    divergence. LDS gather lane-stride = 31 floats (coprime 32) -> conflict
//    free. Slice 19.6KB -> 8 blocks/CU.
//  - global_load_lds width=16 staging (linear dest, no VGPR round-trip).
//  - fwd writes per-block max to ws[p] (all slots written each call -> no
//    memset, no atomics). normalize blocks re-reduce ws from L2 (~5us agg),
//    then scale Y in place (float4) and append H. 2 dispatches total.

#define MDIM    512
#define LBANDS  31
#define WOUT    (MDIM + LBANDS - 1)    // 542
#define BATCH   8
#define ROWELEMS (MDIM * LBANDS)       // 15872
#define CHUNK   128
#define NCHUNK  5                      // 5*128 = 640 >= 542
#define NBLK    (BATCH * MDIM * NCHUNK) // 20480
#define MAXLDSF 4904                   // max slice floats (158*31=4898, +align)

__global__ __launch_bounds__(128, 4) void cassi_fwd_kernel(
    const float* __restrict__ x,      // (B, M, M, L)
    const float* __restrict__ Hm,     // (M, M)
    float* __restrict__ Y,            // (B, M, WOUT), unnormalized
    float* __restrict__ bmaxs)        // ws[0..NBLK)
{
    __shared__ float xs[MAXLDSF];     // 19,616 B
    __shared__ float smax[2];

    const int tid = threadIdx.x;
    const int p   = blockIdx.x;
    // XCD-aware bijective swizzle (20480 % 8 == 0): adjacent units (same row,
    // overlapping slices) land on the same XCD's L2.
    const int lb    = ((p & 7) * (NBLK / 8)) + (p >> 3);
    const int bm    = lb / NCHUNK;          // b*M + m
    const int chunk = lb - bm * NCHUNK;
    const int c0    = chunk * CHUNK;
    const int m     = bm & (MDIM - 1);

    // x slice for cols [c0, c0+ncols): n in [n0, n1]
    int n0 = c0 - (LBANDS - 1); if (n0 < 0) n0 = 0;
    int n1 = c0 + CHUNK - 1;    if (n1 > MDIM - 1) n1 = MDIM - 1;
    const int gb   = (n0 * LBANDS) & ~3;        // 16B-aligned float base
    const int nvec = ((n1 + 1) * LBANDS - gb + 3) >> 2;  // never overruns row

    // ---- stage slice via global->LDS DMA (linear dest, lane-ordered) ----
    const float* __restrict__ xsl = x + (size_t)bm * ROWELEMS + gb;
    for (int v = tid; v < nvec; v += 128)
        __builtin_amdgcn_global_load_lds(
            (const __attribute__((address_space(1))) void*)(xsl + 4 * v),
            (__attribute__((address_space(3))) void*)(xs + 4 * v),
            16, 0, 0);
    __syncthreads();   // drains vmcnt + lgkm before LDS reads

    // ---- gather: lane owns col c0+tid; 31 taps unrolled, masked ----
    const int ncols = (WOUT - c0) < CHUNK ? (WOUT - c0) : CHUNK;
    float lmax = 0.0f;
    if (tid < ncols) {
        const int no = c0 + tid;
        const float* __restrict__ hrow = Hm + m * MDIM;
        const int bn = no - (LBANDS - 1);
        float acc = 0.0f;
        #pragma unroll
        for (int t = 0; t < LBANDS; ++t) {          // l = 30 - t, n = bn + t
            const int n  = bn + t;
            int nc = n;
            nc = nc < 0 ? 0 : nc;
            nc = nc > (MDIM - 1) ? (MDIM - 1) : nc;
            const float hv = (n == nc) ? hrow[nc] : 0.0f;   // cndmask, no branch
            const float xv = xs[nc * LBANDS + (LBANDS - 1 - t) - gb]; // in-bounds
            acc = fmaf(hv, xv, acc);
        }
        Y[(size_t)bm * WOUT + no] = acc;
        lmax = acc;
    }

    // ---- block max -> ws[p] (every slot written every call) ----
    #pragma unroll
    for (int off = 32; off > 0; off >>= 1)
        lmax = fmaxf(lmax, __shfl_down(lmax, off, 64));
    if ((tid & 63) == 0) smax[tid >> 6] = lmax;
    __syncthreads();
    if (tid == 0) bmaxs[p] = fmaxf(smax[0], smax[1]);
}

__global__ __launch_bounds__(256) void cassi_norm_kernel(
    const float* __restrict__ Hm,     // (M, M)
    float* __restrict__ out,          // [Y | H], float4-aligned
    const float* __restrict__ bmaxs,  // NBLK floats (L2-resident)
    int ysize4, int total4)
{
    __shared__ float sred[4];
    // ---- every block reduces the 20480 maxes (80KB, L2-served) ----
    float gm = 0.0f;
    const float4* __restrict__ w4 = (const float4*)bmaxs;
    for (int i = threadIdx.x; i < NBLK / 4; i += 256) {
        const float4 v = w4[i];
        gm = fmaxf(fmaxf(gm, fmaxf(v.x, v.y)), fmaxf(v.z, v.w));
    }
    #pragma unroll
    for (int off = 32; off > 0; off >>= 1)
        gm = fmaxf(gm, __shfl_down(gm, off, 64));
    if ((threadIdx.x & 63) == 0) sred[threadIdx.x >> 6] = gm;
    __syncthreads();
    const float inv = 1.0f /
        fmaxf(fmaxf(sred[0], sred[1]), fmaxf(sred[2], sred[3]));

    const int idx = blockIdx.x * 256 + threadIdx.x;
    if (idx < ysize4) {
        float4* __restrict__ o4 = (float4*)out;
        float4 v = o4[idx];
        v.x *= inv; v.y *= inv; v.z *= inv; v.w *= inv;
        o4[idx] = v;
    } else if (idx < total4) {
        const float4* __restrict__ h4 = (const float4*)Hm;
        ((float4*)out)[idx] = h4[idx - ysize4];
    }
}

extern "C" void kernel_launch(void* const* d_in, const int* in_sizes, int n_in,
                              void* d_out, int out_size, void* d_ws, size_t ws_size,
                              hipStream_t stream) {
    const float* x  = (const float*)d_in[0];   // (8, 512, 512, 31, 1)
    const float* Hm = (const float*)d_in[1];   // (1, 512, 512, 1, 1)
    float* out = (float*)d_out;                // [Y (2,220,032) | H (262,144)]
    float* ws  = (float*)d_ws;                 // NBLK block maxes

    const int ysize4 = (BATCH * MDIM * WOUT) / 4;   // 555,008
    const int total4 = out_size / 4;                // 620,544

    cassi_fwd_kernel<<<NBLK, CHUNK, 0, stream>>>(x, Hm, out, ws);
    cassi_norm_kernel<<<(total4 + 255) / 256, 256, 0, stream>>>(
        Hm, out, ws, ysize4, total4);
}

// Round 7
// 56.901 us; speedup vs baseline: 4.9933x; 1.0528x over previous
//
#include <hip/hip_runtime.h>

// CASSI forward: Y[b,m,no] = sum_l H[m,no-l] * x[b,m,no-l,l], no in [0,542)
// then Y /= max(Y); output = [Y flat | H flat].  B=8, M=512, L=31, S=1.
//
// R7 = R6 with halo/overhead trims:
//  - CHUNK=256, block=256: slice 35.5KB -> 4 blocks/CU (same 16 waves/CU as
//    R6) but halo overfetch 1.23x -> 1.12x and 12288 blocks (was 20480).
//  - norm kernel: 1024 threads/block -> ws re-reduce L2 traffic /4
//    (606 blocks x 48KB = 29MB vs 194MB).
//  - unchanged: global_load_lds width-16 staging (linear dest), fully
//    unrolled clamped+masked 31-tap gather (lane stride 31 floats, coprime
//    with 32 banks -> free), per-block max to ws (all slots written, no
//    memset/atomics), bijective XCD swizzle (12288 % 8 == 0).

#define MDIM    512
#define LBANDS  31
#define WOUT    (MDIM + LBANDS - 1)    // 542
#define BATCH   8
#define ROWELEMS (MDIM * LBANDS)       // 15872
#define CHUNK   256
#define NCHUNK  3                      // 3*256 = 768 >= 542
#define NBLK    (BATCH * MDIM * NCHUNK) // 12288
#define MAXLDSF 8872                   // max slice floats (286*31=8866 +align)

__global__ __launch_bounds__(256, 4) void cassi_fwd_kernel(
    const float* __restrict__ x,      // (B, M, M, L)
    const float* __restrict__ Hm,     // (M, M)
    float* __restrict__ Y,            // (B, M, WOUT), unnormalized
    float* __restrict__ bmaxs)        // ws[0..NBLK)
{
    __shared__ float xs[MAXLDSF];     // 35,488 B
    __shared__ float smax[4];

    const int tid = threadIdx.x;
    const int p   = blockIdx.x;
    // XCD-aware bijective swizzle (12288 % 8 == 0): adjacent units (same row,
    // overlapping halos) land on the same XCD's L2 at the same time.
    const int lb    = ((p & 7) * (NBLK / 8)) + (p >> 3);
    const int bm    = lb / NCHUNK;          // b*M + m
    const int chunk = lb - bm * NCHUNK;
    const int c0    = chunk * CHUNK;
    const int m     = bm & (MDIM - 1);

    // x slice for cols [c0, ...): n in [n0, n1]
    int n0 = c0 - (LBANDS - 1); if (n0 < 0) n0 = 0;
    int n1 = c0 + CHUNK - 1;    if (n1 > MDIM - 1) n1 = MDIM - 1;
    const int gb   = (n0 * LBANDS) & ~3;        // 16B-aligned float base
    const int nvec = ((n1 + 1) * LBANDS - gb + 3) >> 2;  // stays inside row

    // ---- stage slice via global->LDS DMA (linear dest, lane-ordered) ----
    const float* __restrict__ xsl = x + (size_t)bm * ROWELEMS + gb;
    for (int v = tid; v < nvec; v += 256)
        __builtin_amdgcn_global_load_lds(
            (const __attribute__((address_space(1))) void*)(xsl + 4 * v),
            (__attribute__((address_space(3))) void*)(xs + 4 * v),
            16, 0, 0);
    __syncthreads();   // drains vmcnt before LDS reads

    // ---- gather: lane owns col c0+tid; 31 taps unrolled, clamped+masked ----
    const int no = c0 + tid;
    const float* __restrict__ hrow = Hm + m * MDIM;
    const int bn = no - (LBANDS - 1);
    float acc = 0.0f;
    #pragma unroll
    for (int t = 0; t < LBANDS; ++t) {          // l = 30 - t, n = bn + t
        const int n  = bn + t;
        int nc = n;
        nc = nc < 0 ? 0 : nc;
        nc = nc > (MDIM - 1) ? (MDIM - 1) : nc;
        const float hv = (n == nc) ? hrow[nc] : 0.0f;     // cndmask, no branch
        const float xv = xs[nc * LBANDS + (LBANDS - 1 - t) - gb]; // in [n0,n1]
        acc = fmaf(hv, xv, acc);
    }
    float lmax = 0.0f;
    if (no < WOUT) {
        Y[(size_t)bm * WOUT + no] = acc;
        lmax = acc;
    }

    // ---- block max -> ws[p] (every slot written every call) ----
    #pragma unroll
    for (int off = 32; off > 0; off >>= 1)
        lmax = fmaxf(lmax, __shfl_down(lmax, off, 64));
    if ((tid & 63) == 0) smax[tid >> 6] = lmax;
    __syncthreads();
    if (tid == 0)
        bmaxs[p] = fmaxf(fmaxf(smax[0], smax[1]), fmaxf(smax[2], smax[3]));
}

__global__ __launch_bounds__(1024) void cassi_norm_kernel(
    const float* __restrict__ Hm,     // (M, M)
    float* __restrict__ out,          // [Y | H], float4-aligned
    const float* __restrict__ bmaxs,  // NBLK floats (L2-resident)
    int ysize4, int total4)
{
    __shared__ float sred[16];
    // ---- block-wide reduce of the 12288 maxes (48KB, L2-served) ----
    float gm = 0.0f;
    const float4* __restrict__ w4 = (const float4*)bmaxs;
    for (int i = threadIdx.x; i < NBLK / 4; i += 1024) {
        const float4 v = w4[i];
        gm = fmaxf(fmaxf(gm, fmaxf(v.x, v.y)), fmaxf(v.z, v.w));
    }
    #pragma unroll
    for (int off = 32; off > 0; off >>= 1)
        gm = fmaxf(gm, __shfl_down(gm, off, 64));
    if ((threadIdx.x & 63) == 0) sred[threadIdx.x >> 6] = gm;
    __syncthreads();
    float bmax = sred[0];
    #pragma unroll
    for (int i = 1; i < 16; ++i) bmax = fmaxf(bmax, sred[i]);
    const float inv = 1.0f / bmax;

    const int idx = blockIdx.x * 1024 + threadIdx.x;
    if (idx < ysize4) {
        float4* __restrict__ o4 = (float4*)out;
        float4 v = o4[idx];
        v.x *= inv; v.y *= inv; v.z *= inv; v.w *= inv;
        o4[idx] = v;
    } else if (idx < total4) {
        const float4* __restrict__ h4 = (const float4*)Hm;
        ((float4*)out)[idx] = h4[idx - ysize4];
    }
}

extern "C" void kernel_launch(void* const* d_in, const int* in_sizes, int n_in,
                              void* d_out, int out_size, void* d_ws, size_t ws_size,
                              hipStream_t stream) {
    const float* x  = (const float*)d_in[0];   // (8, 512, 512, 31, 1)
    const float* Hm = (const float*)d_in[1];   // (1, 512, 512, 1, 1)
    float* out = (float*)d_out;                // [Y (2,220,032) | H (262,144)]
    float* ws  = (float*)d_ws;                 // NBLK block maxes

    const int ysize4 = (BATCH * MDIM * WOUT) / 4;   // 555,008
    const int total4 = out_size / 4;                // 620,544

    cassi_fwd_kernel<<<NBLK, 256, 0, stream>>>(x, Hm, out, ws);
    cassi_norm_kernel<<<(total4 + 1023) / 1024, 1024, 0, stream>>>(
        Hm, out, ws, ysize4, total4);
}